// Round 1
// baseline (382.389 us; speedup 1.0000x reference)
//
#include <hip/hip_runtime.h>
#include <cstdint>
#include <cstddef>

#define H     1024
#define LSEQ  2048
#define NHH   4
#define DKK   128
#define DVV   256
#define KDIM  512
#define VDIM  1024
#define GRR   64
#define MTOT  4096   // B*L
#define SEGL  128    // scan segment length
#define NSEG  16

enum { EPI_NONE = 0, EPI_TANH = 1, EPI_DEC = 3 };

typedef __attribute__((ext_vector_type(8))) _Float16 half8;
typedef __attribute__((ext_vector_type(4))) float f32x4;
typedef __attribute__((ext_vector_type(2))) float f32x2;

static __device__ __forceinline__ unsigned short f2h(float f) {
    _Float16 h = (_Float16)f;          // v_cvt_f16_f32, RNE
    union { _Float16 h; unsigned short u; } c;
    c.h = h;
    return c.u;
}

// DPP-based partial-wave reduction step: return x + dpp_move(x, CTRL). Pure VALU.
template<int CTRL>
static __device__ __forceinline__ float dpp_add(float x) {
    int xi = __float_as_int(x);
    int mv = __builtin_amdgcn_update_dpp(0, xi, CTRL, 0xf, 0xf, true);
    return x + __int_as_float(mv);
}

// ---------------------------------------------------------------------------
// Fused 5-branch thin-K LERP kernel (replaces gemm_bt<EPI_LERP> with grid z=5).
// Block computes a 64x64 output tile for ALL 5 mixing branches, caching the
// x / shifted-x epilogue tiles in registers across branches (was re-read 5x).
//   in_z[m][n] = x[m][n] + (shift(x)[m][n]-x[m][n]) * ((xp[m,:] @ Wx2_z[n,:]) + xb_z[n])
// ---------------------------------------------------------------------------
__global__ __launch_bounds__(256) void lerp5_kernel(
    const float* __restrict__ xp,      // [4096 x 256] f32 (cols 160.. zero)
    const float* __restrict__ Wx2,     // [1024 x 160] f32
    const float* __restrict__ xb,      // [5 x 1024] f32
    const float* __restrict__ x,       // [4096 x 1024] f32
    unsigned short* __restrict__ insb) // 5 slots x [4096 x 1024] fp16
{
    __shared__ float As[16][64];
    __shared__ float Bs[16][64];
    const int m0 = blockIdx.x * 64;
    const int n0 = blockIdx.y * 64;
    const int t  = threadIdx.x;
    const int tx = t & 15, ty = t >> 4;
    const int sm = t >> 2;          // staging row 0..63
    const int sq = (t & 3) * 4;     // staging k-quad
    const int nbase = n0 + tx * 4;

    // cache epilogue x tiles once for all 5 branches
    float4 xv[4], pv[4];
#pragma unroll
    for (int i = 0; i < 4; i++) {
        const int m = m0 + ty * 4 + i;
        xv[i] = *(const float4*)(x + (size_t)m * H + nbase);
        pv[i] = make_float4(0.f, 0.f, 0.f, 0.f);
        if ((m & (LSEQ - 1)) != 0)
            pv[i] = *(const float4*)(x + (size_t)(m - 1) * H + nbase);
    }

    for (int z = 0; z < 5; z++) {
        const int acol = z * 32;
        float acc[4][4];
#pragma unroll
        for (int i = 0; i < 4; i++)
#pragma unroll
            for (int j = 0; j < 4; j++) acc[i][j] = 0.f;

#pragma unroll
        for (int k0 = 0; k0 < 32; k0 += 16) {
            {   // stage A tile from xp
                const int m = m0 + sm;
                const float4 av = *(const float4*)(xp + (size_t)m * 256 + acol + k0 + sq);
                As[sq + 0][sm] = av.x; As[sq + 1][sm] = av.y;
                As[sq + 2][sm] = av.z; As[sq + 3][sm] = av.w;
            }
            {   // stage B tile from Wx2 (ldb = 160)
                const int n = n0 + sm;
                const float4 bv = *(const float4*)(Wx2 + (size_t)n * 160 + acol + k0 + sq);
                Bs[sq + 0][sm] = bv.x; Bs[sq + 1][sm] = bv.y;
                Bs[sq + 2][sm] = bv.z; Bs[sq + 3][sm] = bv.w;
            }
            __syncthreads();
#pragma unroll
            for (int kk = 0; kk < 16; kk++) {
                const float4 a = *(const float4*)&As[kk][ty * 4];
                const float4 b = *(const float4*)&Bs[kk][tx * 4];
                const float av2[4] = {a.x, a.y, a.z, a.w};
                const float bv2[4] = {b.x, b.y, b.z, b.w};
#pragma unroll
                for (int i = 0; i < 4; i++)
#pragma unroll
                    for (int j = 0; j < 4; j++) acc[i][j] += av2[i] * bv2[j];
            }
            __syncthreads();
        }

        const float4 bb = *(const float4*)(xb + z * H + nbase);
        unsigned short* dst = insb + (size_t)z * 4194304;
#pragma unroll
        for (int i = 0; i < 4; i++) {
            const int m = m0 + ty * 4 + i;
            float4 r;
            r.x = xv[i].x + (pv[i].x - xv[i].x) * (acc[i][0] + bb.x);
            r.y = xv[i].y + (pv[i].y - xv[i].y) * (acc[i][1] + bb.y);
            r.z = xv[i].z + (pv[i].z - xv[i].z) * (acc[i][2] + bb.z);
            r.w = xv[i].w + (pv[i].w - xv[i].w) * (acc[i][3] + bb.w);
            ushort4 p;
            p.x = f2h(r.x); p.y = f2h(r.y); p.z = f2h(r.z); p.w = f2h(r.w);
            *(ushort4*)(dst + (size_t)m * H + nbase) = p;
        }
    }
}

// ---------------------------------------------------------------------------
// fp16 MFMA GEMM (m97 structure): C[m][n] = sum_k A[m][k] * B[n][k].
// A2/nsplit: blocks with n0 >= nsplit read A2.
// EPI_TANH: f32 tanh out.  EPI_DEC: f32 exp(-exp(val+bias[n])) out.
// ---------------------------------------------------------------------------
template<int EPI>
__global__ __launch_bounds__(256) void gemm_mfma_bt(
    const unsigned short* __restrict__ A,
    const unsigned short* __restrict__ A2, int nsplit, int lda,
    const unsigned short* __restrict__ B, int ldb,
    float* __restrict__ C, unsigned short* __restrict__ Ch, int ldc, int K,
    const float* __restrict__ bias)
{
    __shared__ __align__(16) unsigned short As[128 * 32];
    __shared__ __align__(16) unsigned short Bs[128 * 32];
    const int t    = threadIdx.x;
    const int w    = t >> 6;
    const int lane = t & 63;
    const int m0 = blockIdx.x * 128;
    const int n0 = blockIdx.y * 128;
    const unsigned short* Au = (n0 < nsplit) ? A : A2;
    const int mw = (w & 1) * 64;
    const int nw = (w >> 1) * 64;
    const int l15 = lane & 15;
    const int q4  = lane >> 4;

    f32x4 acc[4][4];
#pragma unroll
    for (int i = 0; i < 4; i++)
#pragma unroll
        for (int j = 0; j < 4; j++) {
            f32x4 z = {0.f, 0.f, 0.f, 0.f};
            acc[i][j] = z;
        }

    for (int k0 = 0; k0 < K; k0 += 32) {
        __syncthreads();
#pragma unroll
        for (int jj = 0; jj < 2; jj++) {
            const int c   = w * 128 + jj * 64 + lane;   // 16B chunk id
            const int row = c >> 2;
            const int col = (c & 3) * 8;
            __builtin_amdgcn_global_load_lds(
                (const __attribute__((address_space(1))) void*)(Au + (size_t)(m0 + row) * lda + k0 + col),
                (__attribute__((address_space(3))) void*)((char*)As + (w * 128 + jj * 64) * 16),
                16, 0, 0);
            __builtin_amdgcn_global_load_lds(
                (const __attribute__((address_space(1))) void*)(B + (size_t)(n0 + row) * ldb + k0 + col),
                (__attribute__((address_space(3))) void*)((char*)Bs + (w * 128 + jj * 64) * 16),
                16, 0, 0);
        }
        __syncthreads();

        half8 a[4], b[4];
#pragma unroll
        for (int i = 0; i < 4; i++)
            a[i] = *(const half8*)(As + (mw + i * 16 + l15) * 32 + q4 * 8);
#pragma unroll
        for (int j = 0; j < 4; j++)
            b[j] = *(const half8*)(Bs + (nw + j * 16 + l15) * 32 + q4 * 8);
#pragma unroll
        for (int i = 0; i < 4; i++)
#pragma unroll
            for (int j = 0; j < 4; j++)
                acc[i][j] = __builtin_amdgcn_mfma_f32_16x16x32_f16(a[i], b[j], acc[i][j], 0, 0, 0);
    }

#pragma unroll
    for (int i = 0; i < 4; i++) {
        const int m_base = m0 + mw + i * 16 + q4 * 4;
#pragma unroll
        for (int j = 0; j < 4; j++) {
            const int n = n0 + nw + j * 16 + l15;
#pragma unroll
            for (int r = 0; r < 4; r++) {
                float val = acc[i][j][r];
                if constexpr (EPI == EPI_TANH) {
                    C[(size_t)(m_base + r) * ldc + n] = tanhf(val);
                } else if constexpr (EPI == EPI_DEC) {
                    C[(size_t)(m_base + r) * ldc + n] = expf(-expf(val + bias[n]));
                } else {
                    C[(size_t)(m_base + r) * ldc + n] = val;
                }
            }
        }
    }
}

// ---------------------------------------------------------------------------
// Merged wlow + rk + vg GEMM launch.  All three consume LERP slots, are
// mutually independent, and share K=1024 — the old 32-block wlow launch left
// 87% of the GPU idle while serializing the stream.  grid (32, 25):
//   y == 0   : wlow16 = tanh(in_w16 @ Ww1p^T) fp16   [4096 x 128]
//   y 1..8   : rk = [r|k]   A = in_r / in_k at nsplit 512,  N=1024
//   y 9..24  : vg = [v|g]   A = in_v / in_g at nsplit 1024, N=2048
// ---------------------------------------------------------------------------
__global__ __launch_bounds__(256) void gemm_fused3(
    const unsigned short* __restrict__ s0, const unsigned short* __restrict__ s1,
    const unsigned short* __restrict__ s2, const unsigned short* __restrict__ s3,
    const unsigned short* __restrict__ s4,
    const unsigned short* __restrict__ Ww1p, const unsigned short* __restrict__ Wrb,
    const unsigned short* __restrict__ Wvb,
    unsigned short* __restrict__ wlow16, float* __restrict__ rkB,
    float* __restrict__ vgB)
{
    const int y = blockIdx.y;
    const unsigned short *Au, *Bp;
    float* C = nullptr;
    unsigned short* Ch = nullptr;
    int n0, ldc;
    if (y == 0) {
        Au = s1; Bp = Ww1p; n0 = 0; ldc = 128; Ch = wlow16;
    } else if (y <= 8) {
        n0 = (y - 1) * 128;
        Au = (n0 < 512) ? s0 : s2;
        Bp = Wrb; C = rkB; ldc = 1024;
    } else {
        n0 = (y - 9) * 128;
        Au = (n0 < 1024) ? s3 : s4;
        Bp = Wvb; C = vgB; ldc = 2048;
    }

    __shared__ __align__(16) unsigned short As[128 * 32];
    __shared__ __align__(16) unsigned short Bs[128 * 32];
    const int t    = threadIdx.x;
    const int w    = t >> 6;
    const int lane = t & 63;
    const int m0 = blockIdx.x * 128;
    const int mw = (w & 1) * 64;
    const int nw = (w >> 1) * 64;
    const int l15 = lane & 15;
    const int q4  = lane >> 4;

    f32x4 acc[4][4];
#pragma unroll
    for (int i = 0; i < 4; i++)
#pragma unroll
        for (int j = 0; j < 4; j++) {
            f32x4 z = {0.f, 0.f, 0.f, 0.f};
            acc[i][j] = z;
        }

    for (int k0 = 0; k0 < H; k0 += 32) {
        __syncthreads();
#pragma unroll
        for (int jj = 0; jj < 2; jj++) {
            const int c   = w * 128 + jj * 64 + lane;
            const int row = c >> 2;
            const int col = (c & 3) * 8;
            __builtin_amdgcn_global_load_lds(
                (const __attribute__((address_space(1))) void*)(Au + (size_t)(m0 + row) * H + k0 + col),
                (__attribute__((address_space(3))) void*)((char*)As + (w * 128 + jj * 64) * 16),
                16, 0, 0);
            __builtin_amdgcn_global_load_lds(
                (const __attribute__((address_space(1))) void*)(Bp + (size_t)(n0 + row) * H + k0 + col),
                (__attribute__((address_space(3))) void*)((char*)Bs + (w * 128 + jj * 64) * 16),
                16, 0, 0);
        }
        __syncthreads();

        half8 a[4], b[4];
#pragma unroll
        for (int i = 0; i < 4; i++)
            a[i] = *(const half8*)(As + (mw + i * 16 + l15) * 32 + q4 * 8);
#pragma unroll
        for (int j = 0; j < 4; j++)
            b[j] = *(const half8*)(Bs + (nw + j * 16 + l15) * 32 + q4 * 8);
#pragma unroll
        for (int i = 0; i < 4; i++)
#pragma unroll
            for (int j = 0; j < 4; j++)
                acc[i][j] = __builtin_amdgcn_mfma_f32_16x16x32_f16(a[i], b[j], acc[i][j], 0, 0, 0);
    }

#pragma unroll
    for (int i = 0; i < 4; i++) {
        const int m_base = m0 + mw + i * 16 + q4 * 4;
#pragma unroll
        for (int j = 0; j < 4; j++) {
            const int n = n0 + nw + j * 16 + l15;
#pragma unroll
            for (int r = 0; r < 4; r++) {
                float val = acc[i][j][r];
                if (Ch) Ch[(size_t)(m_base + r) * ldc + n] = f2h(tanhf(val));
                else    C[(size_t)(m_base + r) * ldc + n] = val;
            }
        }
    }
}

// ---------------------------------------------------------------------------
// Batched fp16 MFMA GEMM with C-accumulate (scan correction):
// o[seg,bh][m,n] += sum_k rt16[m,k] * SentryT16[n,k].  M=128, N=256, K=128.
// grid (1, 2, 120): z = (seg-1)*8 + bh.
// ---------------------------------------------------------------------------
__global__ __launch_bounds__(256) void gemm_mfma_corr(
    const unsigned short* __restrict__ rt16,
    const unsigned short* __restrict__ SentryT16,
    float* __restrict__ o)
{
    const int z   = blockIdx.z;
    const int seg = (z >> 3) + 1;
    const int bh  = z & 7;
    const int b   = bh >> 2, h = bh & 3;
    const unsigned short* A = rt16 + ((size_t)b * LSEQ + seg * SEGL) * KDIM + h * DKK;
    const unsigned short* B = SentryT16 + (size_t)(seg * 8 + bh) * 32768;
    float* C = o + ((size_t)b * LSEQ + seg * SEGL) * VDIM + h * DVV;

    __shared__ __align__(16) unsigned short As[128 * 32];
    __shared__ __align__(16) unsigned short Bs[128 * 32];
    const int t    = threadIdx.x;
    const int w    = t >> 6;
    const int lane = t & 63;
    const int m0 = blockIdx.x * 128;
    const int n0 = blockIdx.y * 128;
    const int mw = (w & 1) * 64;
    const int nw = (w >> 1) * 64;
    const int l15 = lane & 15;
    const int q4  = lane >> 4;

    f32x4 acc[4][4];
#pragma unroll
    for (int i = 0; i < 4; i++)
#pragma unroll
        for (int j = 0; j < 4; j++) {
            f32x4 zz = {0.f, 0.f, 0.f, 0.f};
            acc[i][j] = zz;
        }

    for (int k0 = 0; k0 < 128; k0 += 32) {
        __syncthreads();
#pragma unroll
        for (int jj = 0; jj < 2; jj++) {
            const int c   = w * 128 + jj * 64 + lane;
            const int row = c >> 2;
            const int col = (c & 3) * 8;
            __builtin_amdgcn_global_load_lds(
                (const __attribute__((address_space(1))) void*)(A + (size_t)(m0 + row) * KDIM + k0 + col),
                (__attribute__((address_space(3))) void*)((char*)As + (w * 128 + jj * 64) * 16),
                16, 0, 0);
            __builtin_amdgcn_global_load_lds(
                (const __attribute__((address_space(1))) void*)(B + (size_t)(n0 + row) * 128 + k0 + col),
                (__attribute__((address_space(3))) void*)((char*)Bs + (w * 128 + jj * 64) * 16),
                16, 0, 0);
        }
        __syncthreads();

        half8 a[4], bb[4];
#pragma unroll
        for (int i = 0; i < 4; i++)
            a[i] = *(const half8*)(As + (mw + i * 16 + l15) * 32 + q4 * 8);
#pragma unroll
        for (int j = 0; j < 4; j++)
            bb[j] = *(const half8*)(Bs + (nw + j * 16 + l15) * 32 + q4 * 8);
#pragma unroll
        for (int i = 0; i < 4; i++)
#pragma unroll
            for (int j = 0; j < 4; j++)
                acc[i][j] = __builtin_amdgcn_mfma_f32_16x16x32_f16(a[i], bb[j], acc[i][j], 0, 0, 0);
    }

#pragma unroll
    for (int i = 0; i < 4; i++) {
        const int m_base = m0 + mw + i * 16 + q4 * 4;
#pragma unroll
        for (int j = 0; j < 4; j++) {
            const int n = n0 + nw + j * 16 + l15;
#pragma unroll
            for (int rr = 0; rr < 4; rr++)
                C[(size_t)(m_base + rr) * VDIM + n] += acc[i][j][rr];
        }
    }
}

// ---------------------------------------------------------------------------
// prep: fp16 packs (Wr|Wk|Wv|Wg|Wo, padded Wx1/Ww1, Ww2) fused with
// xl = x + (shift(x)-x)*mu_x -> fp16.  blocks 0..4511 = cvt, 4512.. = xl.
// ---------------------------------------------------------------------------
__global__ __launch_bounds__(256) void prep_kernel(
    const float* __restrict__ Wr, const float* __restrict__ Wk,
    const float* __restrict__ Wv, const float* __restrict__ Wg,
    const float* __restrict__ Wo, const float* __restrict__ Wx1,
    const float* __restrict__ Ww1, const float* __restrict__ Ww2,
    unsigned short* __restrict__ Wb, unsigned short* __restrict__ Wx1p,
    unsigned short* __restrict__ Ww1p, unsigned short* __restrict__ Ww2p,
    const float* __restrict__ x, const float* __restrict__ mux,
    unsigned short* __restrict__ xl16)
{
    const int bx = blockIdx.x;
    if (bx < 4512) {
        const int q = bx * 256 + threadIdx.x;   // quad index
        float4 v = make_float4(0.f, 0.f, 0.f, 0.f);
        unsigned short* dst;
        if (q < 1048576) {
            const int i4 = q * 4;
            const float* src; int off;
            if      (i4 <  524288) { src = Wr; off = i4; }
            else if (i4 < 1048576) { src = Wk; off = i4 -  524288; }
            else if (i4 < 2097152) { src = Wv; off = i4 - 1048576; }
            else if (i4 < 3145728) { src = Wg; off = i4 - 2097152; }
            else                   { src = Wo; off = i4 - 3145728; }
            v = *(const float4*)(src + off);
            dst = Wb + i4;
        } else if (q < 1114112) {
            const int e = (q - 1048576) * 4;
            const int row = e >> 10;
            if (row < 160) v = *(const float4*)(Wx1 + (size_t)row * H + (e & 1023));
            dst = Wx1p + e;
        } else if (q < 1146880) {
            const int e = (q - 1114112) * 4;
            const int row = e >> 10;
            if (row < 64) v = *(const float4*)(Ww1 + (size_t)row * H + (e & 1023));
            dst = Ww1p + e;
        } else {
            const int e = (q - 1146880) * 4;       // 32768 contiguous elems
            v = *(const float4*)(Ww2 + e);
            dst = Ww2p + e;
        }
        ushort4 o4;
        o4.x = f2h(v.x); o4.y = f2h(v.y); o4.z = f2h(v.z); o4.w = f2h(v.w);
        *(ushort4*)dst = o4;
    } else {
        const int m = bx - 4512;
        const int c = threadIdx.x * 4;
        const float4 xv = *(const float4*)(x + (size_t)m * H + c);
        float4 pv = make_float4(0.f, 0.f, 0.f, 0.f);
        if ((m & (LSEQ - 1)) != 0)
            pv = *(const float4*)(x + (size_t)(m - 1) * H + c);
        const float4 mv = *(const float4*)(mux + c);
        ushort4 p;
        p.x = f2h(xv.x + (pv.x - xv.x) * mv.x);
        p.y = f2h(xv.y + (pv.y - xv.y) * mv.y);
        p.z = f2h(xv.z + (pv.z - xv.z) * mv.z);
        p.w = f2h(xv.w + (pv.w - xv.w) * mv.w);
        *(ushort4*)(xl16 + (size_t)m * H + c) = p;
    }
}

// ---------------------------------------------------------------------------
// Scan pass 1 v7: 16 segments (TLP: 1024 blocks = 4 waves/SIMD), 4 v-cols per
// thread, packed-f32 math (v_pk_fma_f32), XCD-grouped swizzle, DPP reduce.
// v7: unroll 2 so the cr=nr register rotation is renamed away (~16 movs/iter).
// blockIdx = seg*64 + vc*8 + bh.
// ---------------------------------------------------------------------------
__global__ __launch_bounds__(256, 4) void scan_pass1(
    const float* __restrict__ rk, const float* __restrict__ vg,
    const float* __restrict__ dec, const float* __restrict__ bonus,
    float* __restrict__ o, unsigned short* __restrict__ rt16,
    float* __restrict__ Sloc, float* __restrict__ Dtot)
{
    const int bh  = blockIdx.x & 7;
    const int vc  = (blockIdx.x >> 3) & 7;
    const int seg = blockIdx.x >> 6;           // 0..15
    const int b   = bh >> 2;
    const int h   = bh & 3;
    const int t   = threadIdx.x;
    const int kg  = t & 31;
    const int vl  = t >> 5;
    const bool wlead = (vc == 0) && (vl == 0);

    f32x2 S2[4][2];
    float D[4] = {1.f, 1.f, 1.f, 1.f}, u[4];
#pragma unroll
    for (int j = 0; j < 4; j++) {
        u[j] = bonus[h * DKK + kg * 4 + j];
        f32x2 z = {0.f, 0.f};
        S2[j][0] = z; S2[j][1] = z;
    }

    const size_t row0 = (size_t)b * LSEQ + (size_t)seg * SEGL;
    const float* rp = rk  + row0 * 1024 + h * DKK + kg * 4;   // k at rp+512
    const float* dp = dec + row0 * 512  + h * DKK + kg * 4;
    const float* vp = vg  + row0 * 2048 + h * DVV + vc * 32 + vl * 4;
    float*       op = o   + row0 * 1024 + h * DVV + vc * 32 + vl * 4;
    unsigned short* rt = rt16 + row0 * 512 + h * DKK + kg * 4;

    float4 cr = *(const float4*)rp;
    float4 ck = *(const float4*)(rp + 512);
    float4 cd = *(const float4*)dp;
    float4 cv = *(const float4*)vp;
    rp += 1024; dp += 512; vp += 2048;

#pragma unroll 2
    for (int t0 = 0; t0 < SEGL; ++t0) {
        const float4 nr = *(const float4*)rp;          // last iter reads slack row
        const float4 nk = *(const float4*)(rp + 512);
        const float4 nd = *(const float4*)dp;
        const float4 nv = *(const float4*)vp;
        rp += 1024; dp += 512; vp += 2048;

        if (wlead) {   // r~ = r * D (exclusive cumprod), fp16
            ushort4 p;
            p.x = f2h(cr.x * D[0]); p.y = f2h(cr.y * D[1]);
            p.z = f2h(cr.z * D[2]); p.w = f2h(cr.w * D[3]);
            *(ushort4*)rt = p;
        }
        rt += 512;

        const float ra[4] = {cr.x, cr.y, cr.z, cr.w};
        const float ka[4] = {ck.x, ck.y, ck.z, ck.w};
        const float da[4] = {cd.x, cd.y, cd.z, cd.w};
        f32x2 va2[2];
        va2[0].x = cv.x; va2[0].y = cv.y;
        va2[1].x = cv.z; va2[1].y = cv.w;
        f32x2 part2[2];
        part2[0] = (f32x2){0.f, 0.f};
        part2[1] = (f32x2){0.f, 0.f};
#pragma unroll
        for (int j = 0; j < 4; j++) {
#pragma unroll
            for (int p = 0; p < 2; p++) {
                const f32x2 kv2 = va2[p] * ka[j];
                part2[p] += ra[j] * (S2[j][p] + u[j] * kv2);
                S2[j][p] = da[j] * S2[j][p] + kv2;
            }
            D[j] *= da[j];
        }
        float part[4] = {part2[0].x, part2[0].y, part2[1].x, part2[1].y};
#pragma unroll
        for (int jj = 0; jj < 4; jj++) {
            part[jj] = dpp_add<0xB1>(part[jj]);    // quad_perm xor1
            part[jj] = dpp_add<0x4E>(part[jj]);    // quad_perm xor2
            part[jj] = dpp_add<0x141>(part[jj]);   // row_half_mirror
            part[jj] = dpp_add<0x140>(part[jj]);   // row_mirror
            part[jj] = dpp_add<0x142>(part[jj]);   // row_bcast15
        }
        if (kg == 31) {
            float4 res = make_float4(part[0], part[1], part[2], part[3]);
            *(float4*)op = res;
        }
        op += 1024;
        cr = nr; ck = nk; cd = nd; cv = nv;
    }

    {   // segment-final state [k][vcol] + total decay
        float* sl = Sloc + (size_t)(seg * 8 + bh) * 32768
                    + (size_t)(kg * 4) * 256 + vc * 32 + vl * 4;
#pragma unroll
        for (int j = 0; j < 4; j++) {
            float4 sv = make_float4(S2[j][0].x, S2[j][0].y, S2[j][1].x, S2[j][1].y);
            *(float4*)(sl + j * 256) = sv;
        }
        if (wlead) {
            float* dt = Dtot + (seg * 8 + bh) * 128 + kg * 4;
#pragma unroll
            for (int j = 0; j < 4; j++) dt[j] = D[j];
        }
    }
}

// ---------------------------------------------------------------------------
// Scan pass 2: propagate entry states across 16 segments; Sentry^T as fp16.
// ---------------------------------------------------------------------------
__global__ __launch_bounds__(256) void scan_pass2(
    const float* __restrict__ Sloc, const float* __restrict__ Dtot,
    unsigned short* __restrict__ SentryT16)
{
    const int vc = blockIdx.x & 31;
    const int bh = blockIdx.x >> 5;
    const int t  = threadIdx.x;
    const int kg = t & 31;
    const int vl = t >> 5;

    float S[4] = {0.f, 0.f, 0.f, 0.f};
    for (int p = 0; p < NSEG; p++) {
        unsigned short* st = SentryT16 + (size_t)(p * 8 + bh) * 32768
                             + (size_t)(vc * 8 + vl) * 128 + kg * 4;
        ushort4 pk;
        pk.x = f2h(S[0]); pk.y = f2h(S[1]); pk.z = f2h(S[2]); pk.w = f2h(S[3]);
        *(ushort4*)st = pk;
        if (p < NSEG - 1) {
            const float* sl = Sloc + (size_t)(p * 8 + bh) * 32768
                              + (size_t)(kg * 4) * 256 + vc * 8 + vl;
            const float* dt = Dtot + (p * 8 + bh) * 128 + kg * 4;
#pragma unroll
            for (int j = 0; j < 4; j++) S[j] = dt[j] * S[j] + sl[j * 256];
        }
    }
}

// ---------------------------------------------------------------------------
// Per-head LayerNorm + swish gate -> fp16. g lives in the fused vg buffer.
// ---------------------------------------------------------------------------
__global__ __launch_bounds__(256) void ln_gate_kernel(
    const float* __restrict__ o, const float* __restrict__ vg,
    const float* __restrict__ lnw, const float* __restrict__ lnb,
    unsigned short* __restrict__ out)
{
    const int m    = blockIdx.x;
    const int t    = threadIdx.x;
    const int h    = t >> 6;
    const int lane = t & 63;
    const size_t obase = (size_t)m * VDIM + (size_t)h * DVV + lane * 4;
    const size_t gbase = (size_t)m * 2048 + 1024 + (size_t)h * DVV + lane * 4;
    const float4 ov = *(const float4*)(o + obase);
    float sum = ov.x + ov.y + ov.z + ov.w;
    float sq  = ov.x * ov.x + ov.y * ov.y + ov.z * ov.z + ov.w * ov.w;
#pragma unroll
    for (int off = 1; off < 64; off <<= 1) {
        sum += __shfl_xor(sum, off);
        sq  += __shfl_xor(sq, off);
    }
    const float mean = sum * (1.f / DVV);
    const float var  = sq * (1.f / DVV) - mean * mean;
    const float rstd = rsqrtf(var + 1e-5f);
    const float4 gv = *(const float4*)(vg + gbase);
    const float4 wv = *(const float4*)(lnw + lane * 4);
    const float4 bv = *(const float4*)(lnb + lane * 4);
    float4 res;
    res.x = ((ov.x - mean) * rstd * wv.x + bv.x) * (gv.x / (1.f + expf(-gv.x)));
    res.y = ((ov.y - mean) * rstd * wv.y + bv.y) * (gv.y / (1.f + expf(-gv.y)));
    res.z = ((ov.z - mean) * rstd * wv.z + bv.z) * (gv.z / (1.f + expf(-gv.z)));
    res.w = ((ov.w - mean) * rstd * wv.w + bv.w) * (gv.w / (1.f + expf(-gv.w)));
    ushort4 p;
    p.x = f2h(res.x); p.y = f2h(res.y); p.z = f2h(res.z); p.w = f2h(res.w);
    *(ushort4*)(out + obase) = p;
}

extern "C" void kernel_launch(void* const* d_in, const int* in_sizes, int n_in,
                              void* d_out, int out_size, void* d_ws, size_t ws_size,
                              hipStream_t stream)
{
    const float* x     = (const float*)d_in[0];
    const float* mu_x  = (const float*)d_in[1];
    const float* Wx1   = (const float*)d_in[2];
    const float* Wx2   = (const float*)d_in[3];
    const float* xb    = (const float*)d_in[4];
    const float* Wr    = (const float*)d_in[5];
    const float* Wk    = (const float*)d_in[6];
    const float* Wv    = (const float*)d_in[7];
    const float* Wg    = (const float*)d_in[8];
    const float* Ww1   = (const float*)d_in[9];
    const float* Ww2   = (const float*)d_in[10];
    const float* bw2   = (const float*)d_in[11];
    const float* bonus = (const float*)d_in[12];
    const float* lnw   = (const float*)d_in[13];
    const float* lnb   = (const float*)d_in[14];
    const float* Wo    = (const float*)d_in[15];
    float* out = (float*)d_out;
    (void)in_sizes; (void)n_in; (void)out_size; (void)ws_size;

    float* ws = (float*)d_ws;
    // layout (f32 word offsets):
    unsigned short* Wx1p = (unsigned short*)(ws + 0);         // 256x1024 fp16 = 131072 w
    unsigned short* Ww1p = (unsigned short*)(ws + 131072);    // 128x1024 fp16 = 65536 w
    unsigned short* Ww2p = (unsigned short*)(ws + 196608);    // 512x64 fp16 = 16384 w
    unsigned short* Wb   = (unsigned short*)(ws + 212992);    // packed weights = 2097152 w
    float* xp     = ws + 2310144;                             // 4096x256 f32 = 1048576 w
    unsigned short* wlow16 = (unsigned short*)(ws + 3358720); // 4096x128 fp16 = 262144 w
    float* insB   = ws + 3620864;                             // 5 fp16 slots x 2097152 w
    float* rkB    = ws + 14106624;                            // 4097x1024 f32 (incl slack)
    float* vgB    = ws + 18301952;                            // 4097x2048 f32 (incl slack)
    float* decB   = ws + 26692608;                            // 4097x512 f32 (incl slack)
    // total: 28790272 words (~115 MB)

    unsigned short* insb = (unsigned short*)insB;             // slot n: insb + n*4194304
    unsigned short* Wrb  = Wb;                                // rows 0-1023 = [Wr;Wk]
    unsigned short* Wvb  = Wb + 1048576;                      // rows 0-2047 = [Wv;Wg]
    unsigned short* Wob  = Wb + 3145728;
    unsigned short* xl16 = (unsigned short*)rkB;              // dead before rk GEMM writes
    // scan-time aliases over consumed regions (stream-ordered, verified):
    float*          o       = insB;                                   // slots 0,1 (in_r/in_w consumed)
    unsigned short* rt16    = insb + 2ul * 4194304;                   // slot 2 (in_k consumed)
    float*          Sloc    = insB + 3ul * 2097152;                   // slots 3+4 (in_v/in_g consumed)
    float*          Dtot    = (float*)wlow16;                         // dead after dec GEMM
    unsigned short* SentryT16 = (unsigned short*)decB;                // dead after scan_pass1
    unsigned short* gatedb  = (unsigned short*)(insB + 3ul * 2097152);// slot 3 (Sloc dead after pass2)

    dim3 blk(256);

    prep_kernel<<<dim3(8608), blk, 0, stream>>>(Wr, Wk, Wv, Wg, Wo, Wx1, Ww1, Ww2,
                                                Wb, Wx1p, Ww1p, Ww2p, x, mu_x, xl16);

    // xp = tanh(xl @ Wx1p^T)  [4096 x 256 f32, cols 160.. are zero]
    gemm_mfma_bt<EPI_TANH><<<dim3(32, 2), blk, 0, stream>>>(
        xl16, xl16, 1 << 30, H, Wx1p, H, xp, nullptr, 256, H, nullptr);

    // fused thin-K 5-branch LERP: in_n = x + delta*(xp_n @ Wx2_n^T + x_bias_n) -> fp16 slot n
    lerp5_kernel<<<dim3(64, 16), blk, 0, stream>>>(xp, Wx2, xb, x, insb);

    // merged wlow + rk + vg (all independent consumers of the LERP slots):
    //   wlow16 = tanh(in_w16 @ Ww1p^T) fp16; rk = [r|k]; vg = [v|g]
    gemm_fused3<<<dim3(32, 25), blk, 0, stream>>>(
        insb + 0ul * 4194304, insb + 1ul * 4194304, insb + 2ul * 4194304,
        insb + 3ul * 4194304, insb + 4ul * 4194304,
        Ww1p, Wrb, Wvb, wlow16, rkB, vgB);

    // dec = exp(-exp(wlow16 @ Ww2p^T + bw2))  (fp16 MFMA, K=64)
    gemm_mfma_bt<EPI_DEC><<<dim3(32, 4), blk, 0, stream>>>(
        wlow16, wlow16, 1 << 30, 128, Ww2p, 64, decB, nullptr, KDIM, 64, bw2);

    // segmented RWKV scan (16 segments, XCD-swizzled)
    scan_pass1<<<dim3(1024), blk, 0, stream>>>(rkB, vgB, decB, bonus, o, rt16, Sloc, Dtot);
    scan_pass2<<<dim3(256), blk, 0, stream>>>(Sloc, Dtot, SentryT16);
    gemm_mfma_corr<<<dim3(1, 2, 120), blk, 0, stream>>>(rt16, SentryT16, o);

    // per-head LN + swish gate -> fp16 gated
    ln_gate_kernel<<<dim3(4096), blk, 0, stream>>>(o, vgB, lnw, lnb, gatedb);

    // out = gated @ Wo^T
    gemm_mfma_bt<EPI_NONE><<<dim3(32, 8), blk, 0, stream>>>(
        gatedb, gatedb, 1 << 30, VDIM, Wob, VDIM, out, nullptr, H, VDIM, nullptr);
}